// Round 1
// baseline (558.728 us; speedup 1.0000x reference)
//
#include <hip/hip_runtime.h>
#include <math.h>

// DicepolyTopk: dice loss + mean of top-10% poly1-BCE values over N=16.7M fp32.
// Strategy: histogram selection on float bit patterns (poly1 >= 0 so bits are
// order-preserving). 2 full passes over inputs + 3 tiny kernels.

#define NBINS 4096
#define POLY_EPS 3.1f

struct Ctl {
  double I;           // sum p*t
  double Sp;          // sum p
  double St;          // sum t
  double Sgt;         // sum of poly1 in L1 buckets strictly > b1
  double topk_extra;  // contribution from bucket b1 (computed by select2)
  unsigned int b1;    // L1 bucket containing the k-th largest value
  unsigned int r;     // k - count(strictly greater L1 buckets)
};

__device__ __forceinline__ float poly1_val(float p, float t) {
  float bce = -(t * logf(p) + (1.0f - t) * log1pf(-p));
  float pt = expf(-bce);
  return bce + (1.0f - pt) * POLY_EPS;
}

// ---------------- pass 1: dice sums + L1 histogram -------------------------
__global__ void __launch_bounds__(256) pass1_kernel(
    const float* __restrict__ preds, const float* __restrict__ gts,
    long long n, Ctl* ctl, unsigned int* __restrict__ hist1) {
  __shared__ unsigned int h[NBINS];
  for (int i = threadIdx.x; i < NBINS; i += blockDim.x) h[i] = 0u;
  __syncthreads();

  float I = 0.f, Sp = 0.f, St = 0.f;
  long long n4 = n >> 2;
  const float4* p4 = (const float4*)preds;
  const float4* t4 = (const float4*)gts;
  long long stride = (long long)gridDim.x * blockDim.x;
  long long tid0 = (long long)blockIdx.x * blockDim.x + threadIdx.x;

  for (long long i = tid0; i < n4; i += stride) {
    float4 p = p4[i];
    float4 t = t4[i];
    float ps[4] = {p.x, p.y, p.z, p.w};
    float ts[4] = {t.x, t.y, t.z, t.w};
#pragma unroll
    for (int j = 0; j < 4; ++j) {
      float pp = ps[j], tt = ts[j];
      I += pp * tt;
      Sp += pp;
      St += tt;
      float v = poly1_val(pp, tt);
      atomicAdd(&h[__float_as_uint(v) >> 19], 1u);
    }
  }
  // scalar tail (N is a multiple of 4 here, but stay generic)
  for (long long i = (n4 << 2) + tid0; i < n; i += stride) {
    float pp = preds[i], tt = gts[i];
    I += pp * tt; Sp += pp; St += tt;
    float v = poly1_val(pp, tt);
    atomicAdd(&h[__float_as_uint(v) >> 19], 1u);
  }

  // wave-level reduce, one double atomic per wave
#pragma unroll
  for (int off = 32; off; off >>= 1) {
    I += __shfl_down(I, off, 64);
    Sp += __shfl_down(Sp, off, 64);
    St += __shfl_down(St, off, 64);
  }
  if ((threadIdx.x & 63) == 0) {
    atomicAdd(&ctl->I, (double)I);
    atomicAdd(&ctl->Sp, (double)Sp);
    atomicAdd(&ctl->St, (double)St);
  }

  __syncthreads();
  for (int i = threadIdx.x; i < NBINS; i += blockDim.x) {
    unsigned c = h[i];
    if (c) atomicAdd(&hist1[i], c);
  }
}

// ---------------- select1: find L1 bucket of the k-th value ----------------
__global__ void __launch_bounds__(1024) select1_kernel(
    Ctl* ctl, const unsigned int* __restrict__ hist1, unsigned int K) {
  __shared__ unsigned int chunk[1024];
  int t = threadIdx.x;
  unsigned hl[4];
  unsigned c = 0;
#pragma unroll
  for (int j = 0; j < 4; ++j) { hl[j] = hist1[t * 4 + j]; c += hl[j]; }
  chunk[t] = c;
  __syncthreads();
  // Hillis-Steele inclusive suffix scan
  for (int off = 1; off < 1024; off <<= 1) {
    unsigned add = (t + off < 1024) ? chunk[t + off] : 0u;
    __syncthreads();
    chunk[t] += add;
    __syncthreads();
  }
  unsigned above = (t < 1023) ? chunk[t + 1] : 0u;
  unsigned cum = above;
  for (int j = 3; j >= 0; --j) {
    unsigned nc = cum + hl[j];
    if (cum < K && nc >= K) {  // exactly one (t,j) globally satisfies this
      ctl->b1 = (unsigned)(t * 4 + j);
      ctl->r = K - cum;
    }
    cum = nc;
  }
}

// ---------------- pass 2: sum above b1 + refine within b1 ------------------
__global__ void __launch_bounds__(256) pass2_kernel(
    const float* __restrict__ preds, const float* __restrict__ gts,
    long long n, Ctl* ctl, unsigned int* __restrict__ hist2,
    float* __restrict__ sum2) {
  __shared__ unsigned int h[NBINS];
  __shared__ float s[NBINS];
  for (int i = threadIdx.x; i < NBINS; i += blockDim.x) { h[i] = 0u; s[i] = 0.f; }
  __syncthreads();

  unsigned b1 = ctl->b1;
  double sgt = 0.0;
  long long n4 = n >> 2;
  const float4* p4 = (const float4*)preds;
  const float4* t4 = (const float4*)gts;
  long long stride = (long long)gridDim.x * blockDim.x;
  long long tid0 = (long long)blockIdx.x * blockDim.x + threadIdx.x;

  for (long long i = tid0; i < n4; i += stride) {
    float4 p = p4[i];
    float4 t = t4[i];
    float ps[4] = {p.x, p.y, p.z, p.w};
    float ts[4] = {t.x, t.y, t.z, t.w};
#pragma unroll
    for (int j = 0; j < 4; ++j) {
      float v = poly1_val(ps[j], ts[j]);
      unsigned u = __float_as_uint(v);
      unsigned b = u >> 19;
      if (b > b1) {
        sgt += (double)v;
      } else if (b == b1) {
        unsigned key = (u >> 7) & 0xFFFu;
        atomicAdd(&h[key], 1u);
        atomicAdd(&s[key], v);
      }
    }
  }
  for (long long i = (n4 << 2) + tid0; i < n; i += stride) {
    float v = poly1_val(preds[i], gts[i]);
    unsigned u = __float_as_uint(v);
    unsigned b = u >> 19;
    if (b > b1) {
      sgt += (double)v;
    } else if (b == b1) {
      unsigned key = (u >> 7) & 0xFFFu;
      atomicAdd(&h[key], 1u);
      atomicAdd(&s[key], v);
    }
  }

#pragma unroll
  for (int off = 32; off; off >>= 1) sgt += __shfl_down(sgt, off, 64);
  if ((threadIdx.x & 63) == 0) atomicAdd(&ctl->Sgt, sgt);

  __syncthreads();
  for (int i = threadIdx.x; i < NBINS; i += blockDim.x) {
    unsigned c = h[i];
    if (c) atomicAdd(&hist2[i], c);
    float sv = s[i];
    if (sv != 0.f) atomicAdd(&sum2[i], sv);
  }
}

// ---------------- select2: resolve within bucket b1 ------------------------
__global__ void __launch_bounds__(1024) select2_kernel(
    Ctl* ctl, const unsigned int* __restrict__ hist2,
    const float* __restrict__ sum2) {
  __shared__ unsigned int chunk[1024];
  __shared__ double reds[16];
  __shared__ unsigned int sb2, sr2;
  unsigned K = ctl->r;  // remaining count needed from bucket b1 (>= 1)
  int t = threadIdx.x;
  unsigned hl[4];
  unsigned c = 0;
#pragma unroll
  for (int j = 0; j < 4; ++j) { hl[j] = hist2[t * 4 + j]; c += hl[j]; }
  chunk[t] = c;
  __syncthreads();
  for (int off = 1; off < 1024; off <<= 1) {
    unsigned add = (t + off < 1024) ? chunk[t + off] : 0u;
    __syncthreads();
    chunk[t] += add;
    __syncthreads();
  }
  unsigned above = (t < 1023) ? chunk[t + 1] : 0u;
  unsigned cum = above;
  for (int j = 3; j >= 0; --j) {
    unsigned nc = cum + hl[j];
    if (cum < K && nc >= K) {
      sb2 = (unsigned)(t * 4 + j);
      sr2 = K - cum;
    }
    cum = nc;
  }
  __syncthreads();
  unsigned b2 = sb2;
  unsigned r2 = sr2;
  // exact sum of all sub-buckets strictly above b2
  double loc = 0.0;
#pragma unroll
  for (int j = 0; j < 4; ++j) {
    int bin = t * 4 + j;
    if (bin > (int)b2) loc += (double)sum2[bin];
  }
#pragma unroll
  for (int off = 32; off; off >>= 1) loc += __shfl_down(loc, off, 64);
  if ((t & 63) == 0) reds[t >> 6] = loc;
  __syncthreads();
  if (t == 0) {
    double S2 = 0.0;
    for (int i = 0; i < 16; ++i) S2 += reds[i];
    // ties in sub-bucket b2 span < 128 ulps: use the bin average for the
    // r2 remaining values (error ~1.5e-5 relative, far below tolerance)
    double avg = (double)sum2[b2] / (double)hist2[b2];
    ctl->topk_extra = S2 + (double)r2 * avg;
  }
}

// ---------------- finalize -------------------------------------------------
__global__ void finalize_kernel(const Ctl* __restrict__ ctl,
                                float* __restrict__ out, unsigned int K) {
  if (threadIdx.x == 0 && blockIdx.x == 0) {
    double dice = 1.0 - (2.0 * ctl->I + 1.0) / (ctl->Sp + ctl->St + 1.0);
    double mean_topk = (ctl->Sgt + ctl->topk_extra) / (double)K;
    out[0] = (float)(dice + mean_topk);
  }
}

extern "C" void kernel_launch(void* const* d_in, const int* in_sizes, int n_in,
                              void* d_out, int out_size, void* d_ws,
                              size_t ws_size, hipStream_t stream) {
  const float* preds = (const float*)d_in[0];
  const float* gts = (const float*)d_in[1];
  long long n = (long long)in_sizes[0];
  unsigned int K = (unsigned int)(n * 10 / 100);  // matches int(N*10/100)

  char* ws = (char*)d_ws;
  Ctl* ctl = (Ctl*)ws;                                       // 64 B slot
  unsigned int* hist1 = (unsigned int*)(ws + 64);            // 16 KB
  unsigned int* hist2 = (unsigned int*)(ws + 64 + NBINS * 4);  // 16 KB
  float* sum2 = (float*)(ws + 64 + NBINS * 8);               // 16 KB
  size_t used = 64 + (size_t)NBINS * 12;

  hipMemsetAsync(d_ws, 0, used, stream);

  const int blocks = 2048;
  const int threads = 256;
  pass1_kernel<<<blocks, threads, 0, stream>>>(preds, gts, n, ctl, hist1);
  select1_kernel<<<1, 1024, 0, stream>>>(ctl, hist1, K);
  pass2_kernel<<<blocks, threads, 0, stream>>>(preds, gts, n, ctl, hist2, sum2);
  select2_kernel<<<1, 1024, 0, stream>>>(ctl, hist2, sum2);
  finalize_kernel<<<1, 64, 0, stream>>>(ctl, (float*)d_out, K);
}

// Round 3
// 409.712 us; speedup vs baseline: 1.3637x; 1.3637x over previous
//
#include <hip/hip_runtime.h>

// DicepolyTopk: dice loss + mean of top-10% poly1-BCE values over N=16.7M fp32.
// Histogram selection on float bit patterns (poly1 >= 0 -> bits order-preserving).
// R3: hardware v_log_f32/v_exp_f32 via __builtin_amdgcn_* (avoids glibc macro
// clash with __exp2f), 2-way replicated LDS histogram in pass1, poly1 clamped
// at 0 to keep bins in range.

#define NBINS 4096
#define POLY_EPS 3.1f
#define LN2F 0.69314718056f

struct Ctl {
  double I;           // sum p*t
  double Sp;          // sum p
  double St;          // sum t
  double Sgt;         // sum of poly1 in L1 buckets strictly > b1
  double topk_extra;  // contribution from bucket b1 (computed by select2)
  unsigned int b1;    // L1 bucket containing the k-th largest value
  unsigned int r;     // k - count(strictly greater L1 buckets)
};

// bce in log2 domain: a2=log2(p), b2=log2(1-p); bce2 = -(b2 + t*(a2-b2))
// bce = bce2*ln2 ; pt = 2^(-bce2) ; poly1 = bce + (1-pt)*eps, clamped >= 0.
__device__ __forceinline__ float poly1_val(float p, float t) {
  float a2 = __builtin_amdgcn_logf(p);          // v_log_f32: log2(p)
  float b2 = __builtin_amdgcn_logf(1.0f - p);   // log2(1-p)
  float bce2 = -(b2 + t * (a2 - b2));
  float pt = __builtin_amdgcn_exp2f(-bce2);     // v_exp_f32: 2^(-bce2)
  float v = bce2 * LN2F + (1.0f - pt) * POLY_EPS;
  return v > 0.0f ? v : 0.0f;
}

// ---------------- pass 1: dice sums + L1 histogram (2-way replicated) ------
__global__ void __launch_bounds__(256) pass1_kernel(
    const float* __restrict__ preds, const float* __restrict__ gts,
    long long n, Ctl* ctl, unsigned int* __restrict__ hist1) {
  __shared__ unsigned int h[2 * NBINS];
  for (int i = threadIdx.x; i < 2 * NBINS; i += blockDim.x) h[i] = 0u;
  __syncthreads();

  unsigned hoff = ((threadIdx.x >> 6) & 1) ? NBINS : 0;  // wave-parity replica

  float I = 0.f, Sp = 0.f, St = 0.f;
  long long n4 = n >> 2;
  const float4* p4 = (const float4*)preds;
  const float4* t4 = (const float4*)gts;
  long long stride = (long long)gridDim.x * blockDim.x;
  long long tid0 = (long long)blockIdx.x * blockDim.x + threadIdx.x;

  for (long long i = tid0; i < n4; i += stride) {
    float4 p = p4[i];
    float4 t = t4[i];
    float ps[4] = {p.x, p.y, p.z, p.w};
    float ts[4] = {t.x, t.y, t.z, t.w};
#pragma unroll
    for (int j = 0; j < 4; ++j) {
      float pp = ps[j], tt = ts[j];
      I += pp * tt;
      Sp += pp;
      St += tt;
      float v = poly1_val(pp, tt);
      atomicAdd(&h[hoff + (__float_as_uint(v) >> 19)], 1u);
    }
  }
  for (long long i = (n4 << 2) + tid0; i < n; i += stride) {
    float pp = preds[i], tt = gts[i];
    I += pp * tt; Sp += pp; St += tt;
    float v = poly1_val(pp, tt);
    atomicAdd(&h[hoff + (__float_as_uint(v) >> 19)], 1u);
  }

  // wave-level reduce, one double atomic per wave
#pragma unroll
  for (int off = 32; off; off >>= 1) {
    I += __shfl_down(I, off, 64);
    Sp += __shfl_down(Sp, off, 64);
    St += __shfl_down(St, off, 64);
  }
  if ((threadIdx.x & 63) == 0) {
    atomicAdd(&ctl->I, (double)I);
    atomicAdd(&ctl->Sp, (double)Sp);
    atomicAdd(&ctl->St, (double)St);
  }

  __syncthreads();
  for (int i = threadIdx.x; i < NBINS; i += blockDim.x) {
    unsigned c = h[i] + h[i + NBINS];
    if (c) atomicAdd(&hist1[i], c);
  }
}

// ---------------- select1: find L1 bucket of the k-th value ----------------
__global__ void __launch_bounds__(1024) select1_kernel(
    Ctl* ctl, const unsigned int* __restrict__ hist1, unsigned int K) {
  __shared__ unsigned int chunk[1024];
  int t = threadIdx.x;
  unsigned hl[4];
  unsigned c = 0;
#pragma unroll
  for (int j = 0; j < 4; ++j) { hl[j] = hist1[t * 4 + j]; c += hl[j]; }
  chunk[t] = c;
  __syncthreads();
  for (int off = 1; off < 1024; off <<= 1) {
    unsigned add = (t + off < 1024) ? chunk[t + off] : 0u;
    __syncthreads();
    chunk[t] += add;
    __syncthreads();
  }
  unsigned above = (t < 1023) ? chunk[t + 1] : 0u;
  unsigned cum = above;
  for (int j = 3; j >= 0; --j) {
    unsigned nc = cum + hl[j];
    if (cum < K && nc >= K) {  // exactly one (t,j) globally satisfies this
      ctl->b1 = (unsigned)(t * 4 + j);
      ctl->r = K - cum;
    }
    cum = nc;
  }
}

// ---------------- pass 2: sum above b1 + refine within b1 ------------------
__global__ void __launch_bounds__(256) pass2_kernel(
    const float* __restrict__ preds, const float* __restrict__ gts,
    long long n, Ctl* ctl, unsigned int* __restrict__ hist2,
    float* __restrict__ sum2) {
  __shared__ unsigned int h[NBINS];
  __shared__ float s[NBINS];
  for (int i = threadIdx.x; i < NBINS; i += blockDim.x) { h[i] = 0u; s[i] = 0.f; }
  __syncthreads();

  unsigned b1 = ctl->b1;
  double sgt = 0.0;
  long long n4 = n >> 2;
  const float4* p4 = (const float4*)preds;
  const float4* t4 = (const float4*)gts;
  long long stride = (long long)gridDim.x * blockDim.x;
  long long tid0 = (long long)blockIdx.x * blockDim.x + threadIdx.x;

  for (long long i = tid0; i < n4; i += stride) {
    float4 p = p4[i];
    float4 t = t4[i];
    float ps[4] = {p.x, p.y, p.z, p.w};
    float ts[4] = {t.x, t.y, t.z, t.w};
#pragma unroll
    for (int j = 0; j < 4; ++j) {
      float v = poly1_val(ps[j], ts[j]);
      unsigned u = __float_as_uint(v);
      unsigned b = u >> 19;
      if (b > b1) {
        sgt += (double)v;
      } else if (b == b1) {
        unsigned key = (u >> 7) & 0xFFFu;
        atomicAdd(&h[key], 1u);
        atomicAdd(&s[key], v);
      }
    }
  }
  for (long long i = (n4 << 2) + tid0; i < n; i += stride) {
    float v = poly1_val(preds[i], gts[i]);
    unsigned u = __float_as_uint(v);
    unsigned b = u >> 19;
    if (b > b1) {
      sgt += (double)v;
    } else if (b == b1) {
      unsigned key = (u >> 7) & 0xFFFu;
      atomicAdd(&h[key], 1u);
      atomicAdd(&s[key], v);
    }
  }

#pragma unroll
  for (int off = 32; off; off >>= 1) sgt += __shfl_down(sgt, off, 64);
  if ((threadIdx.x & 63) == 0) atomicAdd(&ctl->Sgt, sgt);

  __syncthreads();
  for (int i = threadIdx.x; i < NBINS; i += blockDim.x) {
    unsigned c = h[i];
    if (c) atomicAdd(&hist2[i], c);
    float sv = s[i];
    if (sv != 0.f) atomicAdd(&sum2[i], sv);
  }
}

// ---------------- select2: resolve within bucket b1 ------------------------
__global__ void __launch_bounds__(1024) select2_kernel(
    Ctl* ctl, const unsigned int* __restrict__ hist2,
    const float* __restrict__ sum2) {
  __shared__ unsigned int chunk[1024];
  __shared__ double reds[16];
  __shared__ unsigned int sb2, sr2;
  unsigned K = ctl->r;  // remaining count needed from bucket b1 (>= 1)
  int t = threadIdx.x;
  unsigned hl[4];
  unsigned c = 0;
#pragma unroll
  for (int j = 0; j < 4; ++j) { hl[j] = hist2[t * 4 + j]; c += hl[j]; }
  chunk[t] = c;
  __syncthreads();
  for (int off = 1; off < 1024; off <<= 1) {
    unsigned add = (t + off < 1024) ? chunk[t + off] : 0u;
    __syncthreads();
    chunk[t] += add;
    __syncthreads();
  }
  unsigned above = (t < 1023) ? chunk[t + 1] : 0u;
  unsigned cum = above;
  for (int j = 3; j >= 0; --j) {
    unsigned nc = cum + hl[j];
    if (cum < K && nc >= K) {
      sb2 = (unsigned)(t * 4 + j);
      sr2 = K - cum;
    }
    cum = nc;
  }
  __syncthreads();
  unsigned b2 = sb2;
  unsigned r2 = sr2;
  double loc = 0.0;
#pragma unroll
  for (int j = 0; j < 4; ++j) {
    int bin = t * 4 + j;
    if (bin > (int)b2) loc += (double)sum2[bin];
  }
#pragma unroll
  for (int off = 32; off; off >>= 1) loc += __shfl_down(loc, off, 64);
  if ((t & 63) == 0) reds[t >> 6] = loc;
  __syncthreads();
  if (t == 0) {
    double S2 = 0.0;
    for (int i = 0; i < 16; ++i) S2 += reds[i];
    // ties in sub-bucket b2 span < 128 ulps: bin average for the r2 remaining
    double avg = (double)sum2[b2] / (double)hist2[b2];
    ctl->topk_extra = S2 + (double)r2 * avg;
  }
}

// ---------------- finalize -------------------------------------------------
__global__ void finalize_kernel(const Ctl* __restrict__ ctl,
                                float* __restrict__ out, unsigned int K) {
  if (threadIdx.x == 0 && blockIdx.x == 0) {
    double dice = 1.0 - (2.0 * ctl->I + 1.0) / (ctl->Sp + ctl->St + 1.0);
    double mean_topk = (ctl->Sgt + ctl->topk_extra) / (double)K;
    out[0] = (float)(dice + mean_topk);
  }
}

extern "C" void kernel_launch(void* const* d_in, const int* in_sizes, int n_in,
                              void* d_out, int out_size, void* d_ws,
                              size_t ws_size, hipStream_t stream) {
  const float* preds = (const float*)d_in[0];
  const float* gts = (const float*)d_in[1];
  long long n = (long long)in_sizes[0];
  unsigned int K = (unsigned int)(n * 10 / 100);  // matches int(N*10/100)

  char* ws = (char*)d_ws;
  Ctl* ctl = (Ctl*)ws;                                         // 64 B slot
  unsigned int* hist1 = (unsigned int*)(ws + 64);              // 16 KB
  unsigned int* hist2 = (unsigned int*)(ws + 64 + NBINS * 4);  // 16 KB
  float* sum2 = (float*)(ws + 64 + NBINS * 8);                 // 16 KB
  size_t used = 64 + (size_t)NBINS * 12;

  (void)hipMemsetAsync(d_ws, 0, used, stream);

  // pass1 uses 32KB LDS -> 5 blocks/CU; 256 CU * 5 = 1280 blocks resident
  const int blocks = 1280;
  const int threads = 256;
  pass1_kernel<<<blocks, threads, 0, stream>>>(preds, gts, n, ctl, hist1);
  select1_kernel<<<1, 1024, 0, stream>>>(ctl, hist1, K);
  pass2_kernel<<<blocks, threads, 0, stream>>>(preds, gts, n, ctl, hist2, sum2);
  select2_kernel<<<1, 1024, 0, stream>>>(ctl, hist2, sum2);
  finalize_kernel<<<1, 64, 0, stream>>>(ctl, (float*)d_out, K);
}

// Round 4
// 209.460 us; speedup vs baseline: 2.6675x; 1.9560x over previous
//
#include <hip/hip_runtime.h>

// DicepolyTopk: dice loss + mean of top-10% poly1-BCE values over N=16.7M fp32.
// Histogram selection on float bit patterns (poly1 >= 0 -> bits order-preserving).
// R4: remove ALL same-address device-scope atomics from the hot passes:
//  - dice/Sgt sums: block-reduce in LDS -> one plain store per block, reduced
//    in finalize (previously 5120 f64 atomics to 1-3 addresses ~= 200 us/pass)
//  - histogram flush: 16x (pass1) / 4x (pass2) global replica histograms
// Hardware v_log_f32/v_exp_f32 via __builtin_amdgcn_*.

#define NBINS 4096
#define NREP1 16
#define NREP2 4
#define GRID1 2048
#define GRID2 1280
#define POLY_EPS 3.1f
#define LN2F 0.69314718056f

struct Ctl {
  double topk_extra;  // contribution from bucket b1 (computed by select2)
  unsigned int b1;    // L1 bucket containing the k-th largest value
  unsigned int r;     // k - count(strictly greater L1 buckets)
};

// bce in log2 domain: a2=log2(p), b2=log2(1-p); bce2 = -(b2 + t*(a2-b2))
// bce = bce2*ln2 ; pt = 2^(-bce2) ; poly1 = bce + (1-pt)*eps, clamped >= 0.
__device__ __forceinline__ float poly1_val(float p, float t) {
  float a2 = __builtin_amdgcn_logf(p);         // v_log_f32: log2(p)
  float b2 = __builtin_amdgcn_logf(1.0f - p);  // log2(1-p)
  float bce2 = -(b2 + t * (a2 - b2));
  float pt = __builtin_amdgcn_exp2f(-bce2);    // v_exp_f32: 2^(-bce2)
  float v = bce2 * LN2F + (1.0f - pt) * POLY_EPS;
  return v > 0.0f ? v : 0.0f;
}

// ---------------- pass 1: dice sums + L1 histogram -------------------------
__global__ void __launch_bounds__(256) pass1_kernel(
    const float* __restrict__ preds, const float* __restrict__ gts,
    long long n, double* __restrict__ blockSums,
    unsigned int* __restrict__ hist1R) {
  __shared__ unsigned int h[NBINS];
  __shared__ double wred[4][3];
  for (int i = threadIdx.x; i < NBINS; i += blockDim.x) h[i] = 0u;
  __syncthreads();

  float I = 0.f, Sp = 0.f, St = 0.f;
  long long n4 = n >> 2;
  const float4* p4 = (const float4*)preds;
  const float4* t4 = (const float4*)gts;
  long long stride = (long long)gridDim.x * blockDim.x;
  long long tid0 = (long long)blockIdx.x * blockDim.x + threadIdx.x;

  for (long long i = tid0; i < n4; i += stride) {
    float4 p = p4[i];
    float4 t = t4[i];
    float ps[4] = {p.x, p.y, p.z, p.w};
    float ts[4] = {t.x, t.y, t.z, t.w};
#pragma unroll
    for (int j = 0; j < 4; ++j) {
      float pp = ps[j], tt = ts[j];
      I += pp * tt;
      Sp += pp;
      St += tt;
      float v = poly1_val(pp, tt);
      atomicAdd(&h[__float_as_uint(v) >> 19], 1u);
    }
  }
  for (long long i = (n4 << 2) + tid0; i < n; i += stride) {
    float pp = preds[i], tt = gts[i];
    I += pp * tt; Sp += pp; St += tt;
    float v = poly1_val(pp, tt);
    atomicAdd(&h[__float_as_uint(v) >> 19], 1u);
  }

  // wave reduce, then cross-wave via LDS, one plain store per block (NO atomics)
  double dI = I, dSp = Sp, dSt = St;
#pragma unroll
  for (int off = 32; off; off >>= 1) {
    dI += __shfl_down(dI, off, 64);
    dSp += __shfl_down(dSp, off, 64);
    dSt += __shfl_down(dSt, off, 64);
  }
  if ((threadIdx.x & 63) == 0) {
    int w = threadIdx.x >> 6;
    wred[w][0] = dI; wred[w][1] = dSp; wred[w][2] = dSt;
  }
  __syncthreads();
  if (threadIdx.x == 0) {
    double a = 0, b = 0, c = 0;
#pragma unroll
    for (int w = 0; w < 4; ++w) { a += wred[w][0]; b += wred[w][1]; c += wred[w][2]; }
    blockSums[blockIdx.x * 3 + 0] = a;
    blockSums[blockIdx.x * 3 + 1] = b;
    blockSums[blockIdx.x * 3 + 2] = c;
  }

  // flush to one of NREP1 replica histograms to spread per-address contention
  unsigned int* dst = hist1R + (size_t)(blockIdx.x & (NREP1 - 1)) * NBINS;
  for (int i = threadIdx.x; i < NBINS; i += blockDim.x) {
    unsigned c = h[i];
    if (c) atomicAdd(&dst[i], c);
  }
}

// ---------------- select1: find L1 bucket of the k-th value ----------------
__global__ void __launch_bounds__(1024) select1_kernel(
    Ctl* ctl, const unsigned int* __restrict__ hist1R, unsigned int K) {
  __shared__ unsigned int chunk[1024];
  int t = threadIdx.x;
  unsigned hl[4];
  unsigned c = 0;
#pragma unroll
  for (int j = 0; j < 4; ++j) {
    unsigned s = 0;
    for (int r = 0; r < NREP1; ++r) s += hist1R[(size_t)r * NBINS + t * 4 + j];
    hl[j] = s;
    c += s;
  }
  chunk[t] = c;
  __syncthreads();
  for (int off = 1; off < 1024; off <<= 1) {
    unsigned add = (t + off < 1024) ? chunk[t + off] : 0u;
    __syncthreads();
    chunk[t] += add;
    __syncthreads();
  }
  unsigned above = (t < 1023) ? chunk[t + 1] : 0u;
  unsigned cum = above;
  for (int j = 3; j >= 0; --j) {
    unsigned nc = cum + hl[j];
    if (cum < K && nc >= K) {  // exactly one (t,j) globally satisfies this
      ctl->b1 = (unsigned)(t * 4 + j);
      ctl->r = K - cum;
    }
    cum = nc;
  }
}

// ---------------- pass 2: sum above b1 + refine within b1 ------------------
__global__ void __launch_bounds__(256) pass2_kernel(
    const float* __restrict__ preds, const float* __restrict__ gts,
    long long n, const Ctl* __restrict__ ctl, double* __restrict__ blockSgt,
    unsigned int* __restrict__ hist2R, float* __restrict__ sum2R) {
  __shared__ unsigned int h[NBINS];
  __shared__ float s[NBINS];
  __shared__ double wred[4];
  for (int i = threadIdx.x; i < NBINS; i += blockDim.x) { h[i] = 0u; s[i] = 0.f; }
  __syncthreads();

  unsigned b1 = ctl->b1;
  double sgt = 0.0;
  long long n4 = n >> 2;
  const float4* p4 = (const float4*)preds;
  const float4* t4 = (const float4*)gts;
  long long stride = (long long)gridDim.x * blockDim.x;
  long long tid0 = (long long)blockIdx.x * blockDim.x + threadIdx.x;

  for (long long i = tid0; i < n4; i += stride) {
    float4 p = p4[i];
    float4 t = t4[i];
    float ps[4] = {p.x, p.y, p.z, p.w};
    float ts[4] = {t.x, t.y, t.z, t.w};
#pragma unroll
    for (int j = 0; j < 4; ++j) {
      float v = poly1_val(ps[j], ts[j]);
      unsigned u = __float_as_uint(v);
      unsigned b = u >> 19;
      if (b > b1) {
        sgt += (double)v;
      } else if (b == b1) {
        unsigned key = (u >> 7) & 0xFFFu;
        atomicAdd(&h[key], 1u);
        atomicAdd(&s[key], v);
      }
    }
  }
  for (long long i = (n4 << 2) + tid0; i < n; i += stride) {
    float v = poly1_val(preds[i], gts[i]);
    unsigned u = __float_as_uint(v);
    unsigned b = u >> 19;
    if (b > b1) {
      sgt += (double)v;
    } else if (b == b1) {
      unsigned key = (u >> 7) & 0xFFFu;
      atomicAdd(&h[key], 1u);
      atomicAdd(&s[key], v);
    }
  }

#pragma unroll
  for (int off = 32; off; off >>= 1) sgt += __shfl_down(sgt, off, 64);
  if ((threadIdx.x & 63) == 0) wred[threadIdx.x >> 6] = sgt;
  __syncthreads();
  if (threadIdx.x == 0)
    blockSgt[blockIdx.x] = wred[0] + wred[1] + wred[2] + wred[3];

  unsigned int* hd = hist2R + (size_t)(blockIdx.x & (NREP2 - 1)) * NBINS;
  float* sd = sum2R + (size_t)(blockIdx.x & (NREP2 - 1)) * NBINS;
  for (int i = threadIdx.x; i < NBINS; i += blockDim.x) {
    unsigned c = h[i];
    if (c) atomicAdd(&hd[i], c);
    float sv = s[i];
    if (sv != 0.f) atomicAdd(&sd[i], sv);
  }
}

// ---------------- select2: resolve within bucket b1 ------------------------
__global__ void __launch_bounds__(1024) select2_kernel(
    Ctl* ctl, const unsigned int* __restrict__ hist2R,
    const float* __restrict__ sum2R) {
  __shared__ unsigned int chunk[1024];
  __shared__ double reds[16];
  __shared__ unsigned int sb2, sr2;
  unsigned K = ctl->r;  // remaining count needed from bucket b1 (>= 1)
  int t = threadIdx.x;
  unsigned hl[4];
  float sl[4];
  unsigned c = 0;
#pragma unroll
  for (int j = 0; j < 4; ++j) {
    unsigned hs = 0;
    float ss = 0.f;
    for (int r = 0; r < NREP2; ++r) {
      hs += hist2R[(size_t)r * NBINS + t * 4 + j];
      ss += sum2R[(size_t)r * NBINS + t * 4 + j];
    }
    hl[j] = hs;
    sl[j] = ss;
    c += hs;
  }
  chunk[t] = c;
  __syncthreads();
  for (int off = 1; off < 1024; off <<= 1) {
    unsigned add = (t + off < 1024) ? chunk[t + off] : 0u;
    __syncthreads();
    chunk[t] += add;
    __syncthreads();
  }
  unsigned above = (t < 1023) ? chunk[t + 1] : 0u;
  unsigned cum = above;
  for (int j = 3; j >= 0; --j) {
    unsigned nc = cum + hl[j];
    if (cum < K && nc >= K) {
      sb2 = (unsigned)(t * 4 + j);
      sr2 = K - cum;
    }
    cum = nc;
  }
  __syncthreads();
  unsigned b2 = sb2;
  unsigned r2 = sr2;
  // exact sum of sub-buckets strictly above b2; track b2's own count/sum
  double loc = 0.0;
  double b2sum = 0.0, b2cnt = 0.0;
#pragma unroll
  for (int j = 0; j < 4; ++j) {
    int bin = t * 4 + j;
    if (bin > (int)b2) loc += (double)sl[j];
    if (bin == (int)b2) { b2sum = (double)sl[j]; b2cnt = (double)hl[j]; }
  }
#pragma unroll
  for (int off = 32; off; off >>= 1) {
    loc += __shfl_down(loc, off, 64);
    b2sum += __shfl_down(b2sum, off, 64);
    b2cnt += __shfl_down(b2cnt, off, 64);
  }
  if ((t & 63) == 0) reds[t >> 6] = loc;
  __syncthreads();
  // b2sum/b2cnt live only in the wave containing bin b2; broadcast via LDS
  __shared__ double sb2sum, sb2cnt;
  if ((t & 63) == 0 && b2cnt != 0.0) { sb2sum = b2sum; sb2cnt = b2cnt; }
  __syncthreads();
  if (t == 0) {
    double S2 = 0.0;
    for (int i = 0; i < 16; ++i) S2 += reds[i];
    // ties in sub-bucket b2 span < 128 ulps: bin average for the r2 remaining
    double avg = sb2sum / sb2cnt;
    ctl->topk_extra = S2 + (double)r2 * avg;
  }
}

// ---------------- finalize: reduce per-block partials + combine ------------
__global__ void __launch_bounds__(256) finalize_kernel(
    const Ctl* __restrict__ ctl, const double* __restrict__ blockSums,
    const double* __restrict__ blockSgt, float* __restrict__ out,
    unsigned int K) {
  __shared__ double red[4][4];
  double I = 0, Sp = 0, St = 0, Sg = 0;
  for (int i = threadIdx.x; i < GRID1; i += 256) {
    I += blockSums[i * 3 + 0];
    Sp += blockSums[i * 3 + 1];
    St += blockSums[i * 3 + 2];
  }
  for (int i = threadIdx.x; i < GRID2; i += 256) Sg += blockSgt[i];
#pragma unroll
  for (int off = 32; off; off >>= 1) {
    I += __shfl_down(I, off, 64);
    Sp += __shfl_down(Sp, off, 64);
    St += __shfl_down(St, off, 64);
    Sg += __shfl_down(Sg, off, 64);
  }
  if ((threadIdx.x & 63) == 0) {
    int w = threadIdx.x >> 6;
    red[w][0] = I; red[w][1] = Sp; red[w][2] = St; red[w][3] = Sg;
  }
  __syncthreads();
  if (threadIdx.x == 0) {
    double tI = 0, tSp = 0, tSt = 0, tSg = 0;
#pragma unroll
    for (int w = 0; w < 4; ++w) {
      tI += red[w][0]; tSp += red[w][1]; tSt += red[w][2]; tSg += red[w][3];
    }
    double dice = 1.0 - (2.0 * tI + 1.0) / (tSp + tSt + 1.0);
    double mean_topk = (tSg + ctl->topk_extra) / (double)K;
    out[0] = (float)(dice + mean_topk);
  }
}

extern "C" void kernel_launch(void* const* d_in, const int* in_sizes, int n_in,
                              void* d_out, int out_size, void* d_ws,
                              size_t ws_size, hipStream_t stream) {
  const float* preds = (const float*)d_in[0];
  const float* gts = (const float*)d_in[1];
  long long n = (long long)in_sizes[0];
  unsigned int K = (unsigned int)(n * 10 / 100);  // matches int(N*10/100)

  char* ws = (char*)d_ws;
  Ctl* ctl = (Ctl*)ws;                                   // @0,      64 B
  double* blockSums = (double*)(ws + 64);                // GRID1*3 doubles = 49152
  double* blockSgt = (double*)(ws + 64 + 49152);         // GRID2 doubles (pad to 16384)
  unsigned int* hist1R = (unsigned int*)(ws + 65600);    // NREP1*NBINS u32 = 262144
  unsigned int* hist2R = (unsigned int*)(ws + 327744);   // NREP2*NBINS u32 = 65536
  float* sum2R = (float*)(ws + 393280);                  // NREP2*NBINS f32 = 65536
  size_t used = 458816;

  (void)hipMemsetAsync(d_ws, 0, used, stream);

  pass1_kernel<<<GRID1, 256, 0, stream>>>(preds, gts, n, blockSums, hist1R);
  select1_kernel<<<1, 1024, 0, stream>>>(ctl, hist1R, K);
  pass2_kernel<<<GRID2, 256, 0, stream>>>(preds, gts, n, ctl, blockSgt, hist2R, sum2R);
  select2_kernel<<<1, 1024, 0, stream>>>(ctl, hist2R, sum2R);
  finalize_kernel<<<1, 256, 0, stream>>>(ctl, blockSums, blockSgt, (float*)d_out, K);
}